// Round 12
// baseline (391.054 us; speedup 1.0000x reference)
//
#include <hip/hip_runtime.h>
#include <hip/hip_bf16.h>
#include <cstdint>

#define AS1 __attribute__((address_space(1)))
#define AS3 __attribute__((address_space(3)))

typedef __bf16 bf16x8 __attribute__((ext_vector_type(8)));
typedef float  f32x16 __attribute__((ext_vector_type(16)));

__device__ __forceinline__ void gld_lds16(const void* g, void* l) {
    __builtin_amdgcn_global_load_lds((const AS1 void*)g, (AS3 void*)l, 16, 0, 0);
}

// ---------------- Kernel 1: conv1 + relu -> channel-last padded bf16 h ----------------
// Side jobs: blocks <1152 build GEMM A; blocks 1152..2327 build fwT[point][12]
// (transposed+padded fc_w: fwT[(a*784+rr)*12 + c] = fw[c*25088 + a*784 + rr], c<10).
// hl layout: [b][yy 0..29][xx 0..29][c 0..127], borders = 0.
__global__ __launch_bounds__(256) void k_conv1(const float* __restrict__ x,
                                               const float* __restrict__ base,
                                               const float* __restrict__ w2,
                                               const float* __restrict__ fw,
                                               __hip_bfloat16* __restrict__ hl,
                                               __hip_bfloat16* __restrict__ A,
                                               float* __restrict__ fwT) {
    int tid = threadIdx.x;

    if (blockIdx.x < 1152) {
        int i = blockIdx.x * 256 + tid;
        int r = i / 1152, k = i - r * 1152;
        int g = r >> 5, o2 = r & 31;
        int kk = k >> 7, cch = k & 127;
        int ky = kk / 3, kx = kk - ky * 3;
        int c2 = cch >> 3, hh = cch & 7;
        int gi = (g - hh) & 7;
        A[i] = __float2bfloat16(w2[((o2 * 16 + c2) * 8 + gi) * 9 + ky * 3 + kx]);
    } else if (blockIdx.x < 2328) {
        int i = (blockIdx.x - 1152) * 256 + tid;      // < 301056 = 25088*12 exact
        int point = i / 12, c = i - point * 12;
        fwT[i] = (c < 10) ? fw[c * 25088 + point] : 0.0f;
    }

    __shared__ float w1s[1152];
    if (tid < 128) {
        int g = tid >> 4, o = tid & 15;
        float th = 6.28318530717958647692f * (float)g / 8.0f;
        float c = cosf(th), s = sinf(th);
        for (int i = 0; i < 3; ++i) {
            float ys = (2.0f * i + 1.0f) / 3.0f - 1.0f;
            for (int j = 0; j < 3; ++j) {
                float xs = (2.0f * j + 1.0f) / 3.0f - 1.0f;
                float gx = c * xs - s * ys;
                float gy = s * xs + c * ys;
                float px = ((gx + 1.0f) * 3.0f - 1.0f) * 0.5f;
                float py = ((gy + 1.0f) * 3.0f - 1.0f) * 0.5f;
                float x0 = floorf(px), y0 = floorf(py);
                float wx = px - x0, wy = py - y0;
                int x0i = (int)x0, y0i = (int)y0;
                auto gat = [&](int yi, int xi) -> float {
                    bool v = (yi >= 0) && (yi < 3) && (xi >= 0) && (xi < 3);
                    int yc = min(max(yi, 0), 2), xc = min(max(xi, 0), 2);
                    return v ? base[o * 9 + yc * 3 + xc] : 0.0f;
                };
                w1s[tid * 9 + i * 3 + j] =
                      gat(y0i, x0i)         * (1.0f - wx) * (1.0f - wy)
                    + gat(y0i, x0i + 1)     * wx          * (1.0f - wy)
                    + gat(y0i + 1, x0i)     * (1.0f - wx) * wy
                    + gat(y0i + 1, x0i + 1) * wx          * wy;
            }
        }
    }
    __syncthreads();

    const int c0 = (tid & 15) * 8;
    float wreg[8][9];
#pragma unroll
    for (int cc = 0; cc < 8; ++cc)
#pragma unroll
        for (int k = 0; k < 9; ++k) wreg[cc][k] = w1s[(c0 + cc) * 9 + k];

    const int slot = tid >> 4;                    // 0..15
    const int band = blockIdx.x % 15;
    const int b    = blockIdx.x / 15;
    const int yy   = band * 2 + (slot >> 3);      // padded row 0..29
    const int xx0  = (slot & 7) * 4;              // 0,4,...,28

    const float* xb = x + b * 784;
    float xv[3][6];
#pragma unroll
    for (int t = 0; t < 3; ++t) {
        int sy = yy - 2 + t;
        bool syok = (sy >= 0) && (sy < 28);
#pragma unroll
        for (int u = 0; u < 6; ++u) {
            int sx = xx0 - 2 + u;
            bool ok = syok && (sx >= 0) && (sx < 28);
            xv[t][u] = ok ? xb[sy * 28 + sx] : 0.0f;
        }
    }

    float acc[4][8];
#pragma unroll
    for (int j = 0; j < 4; ++j)
#pragma unroll
        for (int cc = 0; cc < 8; ++cc) acc[j][cc] = 0.0f;

#pragma unroll
    for (int t = 0; t < 3; ++t)
#pragma unroll
        for (int u = 0; u < 3; ++u) {
#pragma unroll
            for (int j = 0; j < 4; ++j) {
                float xvv = xv[t][j + u];
#pragma unroll
                for (int cc = 0; cc < 8; ++cc)
                    acc[j][cc] += xvv * wreg[cc][t * 3 + u];
            }
        }

#pragma unroll
    for (int j = 0; j < 4; ++j) {
        int xx = xx0 + j;
        if (xx < 30) {
            bool interior = (yy >= 1) && (yy <= 28) && (xx >= 1) && (xx <= 28);
            union { __hip_bfloat16 h[8]; float4 f4; } u;
#pragma unroll
            for (int cc = 0; cc < 8; ++cc)
                u.h[cc] = __float2bfloat16(interior ? fmaxf(acc[j][cc], 0.0f) : 0.0f);
            int pi = b * 900 + yy * 30 + xx;
            *(float4*)(hl + (size_t)pi * 128 + c0) = u.f4;
        }
    }
}

// ---------------- Kernel 2: conv2 implicit GEMM (32x32x16) + relu + pool + FUSED FC ----
// R11 proven core: M=128 x N=128, BK=64, 18 stages, XCD-paired mt halves, conflict-free
// swizzle. Fused FC v3: coalesced fwT loads (3x float4 per (a,pixel)) + wave shfl-tree
// reduction + 20 atomics/block. No p buffer, no fc kernel.
__global__ __launch_bounds__(256) void k_conv2(const __hip_bfloat16* __restrict__ A,
                                               const __hip_bfloat16* __restrict__ hl,
                                               const float* __restrict__ fwT,
                                               const float* __restrict__ fb,
                                               float* __restrict__ out) {
    __shared__ __align__(16) char smem[32768];   // staging; reused as wred[80] floats

    const int tid  = threadIdx.x;
    const int lane = tid & 63;
    const int w    = tid >> 6;
    const int wr   = w >> 1, wc = w & 1;
    const int hi   = lane >> 5;           // K-half selector

    const int bid  = blockIdx.x;          // grid 6272 = 8 * 784
    const int xcd  = bid & 7;
    const int slot = bid >> 3;
    const int nt   = xcd + 8 * (slot >> 1);   // < 3136
    const int mt   = slot & 1;
    const int n0 = nt << 7;
    const int r0 = mt << 7;

    uint32_t aG[4], bG[4], ldsOff[4];
#pragma unroll
    for (int q = 0; q < 4; ++q) {
        int ch = w * 4 + q;
        int rl = ch * 8 + (lane >> 3);
        int ca = (lane & 7) ^ (rl & 7) ^ (ch & 3);
        aG[q] = (uint32_t)((r0 + rl) * 2304 + ca * 16);
        int n  = n0 + rl;
        int b  = n / 784; int rr = n - b * 784;
        int y  = rr / 28; int xx = rr - y * 28;
        bG[q]  = (uint32_t)(((b * 30 + y) * 30 + xx) * 256 + ca * 16);
        ldsOff[q] = (uint32_t)(ch * 1024);
    }

    uint32_t aro[2], bro[2]; int asw[2], bsw[2];
#pragma unroll
    for (int t = 0; t < 2; ++t) {
        int rl = 64 * wr + 32 * t + (lane & 31);
        aro[t] = (uint32_t)(rl * 128); asw[t] = (rl & 7) ^ ((rl >> 3) & 3);
        int nl = 64 * wc + 32 * t + (lane & 31);
        bro[t] = (uint32_t)(16384 + nl * 128); bsw[t] = (nl & 7) ^ ((nl >> 3) & 3);
    }

    f32x16 acc[2][2];
#pragma unroll
    for (int i = 0; i < 2; ++i)
#pragma unroll
        for (int j = 0; j < 2; ++j) acc[i][j] = (f32x16)(0.0f);

    const char* Ab = (const char*)A;
    const char* Hb = (const char*)hl;

    for (int s = 0; s < 18; ++s) {
        int kk = s >> 1, half = s & 1;
        int ky = kk / 3, kx = kk - ky * 3;
        int aoff = kk * 256 + half * 128;
        int boff = (ky * 30 + kx) * 256 + half * 128;

        __syncthreads();
#pragma unroll
        for (int q = 0; q < 4; ++q) {
            gld_lds16(Ab + aG[q] + aoff, smem + ldsOff[q]);
            gld_lds16(Hb + bG[q] + boff, smem + 16384 + ldsOff[q]);
        }
        __syncthreads();

#pragma unroll
        for (int kstep = 0; kstep < 4; ++kstep) {
            int cb = kstep * 2 + hi;
            bf16x8 af[2], bf[2];
#pragma unroll
            for (int t = 0; t < 2; ++t) {
                af[t] = *(const bf16x8*)(smem + aro[t] + ((cb ^ asw[t]) * 16));
                bf[t] = *(const bf16x8*)(smem + bro[t] + ((cb ^ bsw[t]) * 16));
            }
#pragma unroll
            for (int i = 0; i < 2; ++i)
#pragma unroll
                for (int j = 0; j < 2; ++j)
                    acc[i][j] = __builtin_amdgcn_mfma_f32_32x32x16_bf16(af[i], bf[j], acc[i][j], 0, 0, 0);
        }
    }

    // ---------- epilogue: relu + 8-row mean -> fused FC (coalesced fwT) ----------
    float accfc[2][10];
    int bb_[2], rr_[2];
#pragma unroll
    for (int tj = 0; tj < 2; ++tj) {
#pragma unroll
        for (int c = 0; c < 10; ++c) accfc[tj][c] = 0.0f;
        int n = n0 + 64 * wc + 32 * tj + (lane & 31);
        int b = n / 784;
        bb_[tj] = b; rr_[tj] = n - b * 784;
    }
    const int qlo = hi * 2;   // hi==0 handles q 0,1; hi==1 handles q 2,3
#pragma unroll
    for (int ti = 0; ti < 2; ++ti) {
        int gbase = (r0 + 64 * wr + 32 * ti) >> 3;
#pragma unroll
        for (int tj = 0; tj < 2; ++tj) {
            f32x16 v = acc[ti][tj];
#pragma unroll
            for (int q = 0; q < 4; ++q) {
                float s = fmaxf(v[4*q], 0.0f) + fmaxf(v[4*q+1], 0.0f)
                        + fmaxf(v[4*q+2], 0.0f) + fmaxf(v[4*q+3], 0.0f);
                s += __shfl_xor(s, 32, 64);      // both halves hold pooled sum
                if (q >= qlo && q < qlo + 2) {
                    float sp = s * 0.125f;
                    int a = gbase + q;
                    const float4* fwp = (const float4*)(fwT + (size_t)(a * 784 + rr_[tj]) * 12);
                    float4 u0 = fwp[0], u1 = fwp[1], u2 = fwp[2];
                    accfc[tj][0] += sp * u0.x; accfc[tj][1] += sp * u0.y;
                    accfc[tj][2] += sp * u0.z; accfc[tj][3] += sp * u0.w;
                    accfc[tj][4] += sp * u1.x; accfc[tj][5] += sp * u1.y;
                    accfc[tj][6] += sp * u1.z; accfc[tj][7] += sp * u1.w;
                    accfc[tj][8] += sp * u2.x; accfc[tj][9] += sp * u2.y;
                }
            }
        }
    }

    // bucket by batch (tile spans <= 2 batches), constant-indexed
    const int b0 = n0 / 784;
    const bool sec0 = (bb_[0] != b0);
    const bool sec1 = (bb_[1] != b0);
    float val[20];
#pragma unroll
    for (int c = 0; c < 10; ++c) {
        float a0 = accfc[0][c], a1 = accfc[1][c];
        val[c]      = (sec0 ? 0.0f : a0) + (sec1 ? 0.0f : a1);
        val[10 + c] = (sec0 ? a0 : 0.0f) + (sec1 ? a1 : 0.0f);
    }

    // wave shfl tree, then 4x20 smem, then 20 atomics
#pragma unroll
    for (int c = 0; c < 20; ++c) {
#pragma unroll
        for (int o = 32; o > 0; o >>= 1) val[c] += __shfl_down(val[c], o, 64);
    }

    __syncthreads();                       // all waves done with smem frag reads
    float* wred = (float*)smem;
    if (lane == 0) {
#pragma unroll
        for (int c = 0; c < 20; ++c) wred[w * 20 + c] = val[c];
    }
    __syncthreads();
    if (tid < 20) {
        float s = wred[tid] + wred[20 + tid] + wred[40 + tid] + wred[60 + tid];
        int idx = tid / 10, c = tid - idx * 10;
        int b = b0 + idx;
        if (b < 512) {
            // bias added exactly once: by the mt==0 block containing batch b's pixel 0
            if (mt == 0 && b * 784 >= n0 && b * 784 < n0 + 128) s += fb[c];
            atomicAdd(&out[b * 10 + c], s);
        }
    }
}

// ---------------- launch ----------------
extern "C" void kernel_launch(void* const* d_in, const int* in_sizes, int n_in,
                              void* d_out, int out_size, void* d_ws, size_t ws_size,
                              hipStream_t stream) {
    const float* x  = (const float*)d_in[0];
    const float* bw = (const float*)d_in[1];
    const float* w2 = (const float*)d_in[2];
    const float* fw = (const float*)d_in[3];
    const float* fb = (const float*)d_in[4];
    float* out = (float*)d_out;
    char* ws = (char*)d_ws;

    __hip_bfloat16* Amat = (__hip_bfloat16*)(ws + 4608);
    __hip_bfloat16* hl   = (__hip_bfloat16*)(ws + 594432);
    float*          fwT  = (float*)(ws + 118563328);

    hipMemsetAsync(d_out, 0, (size_t)out_size * sizeof(float), stream);
    k_conv1<<<7680, 256, 0, stream>>>(x, bw, w2, fw, hl, Amat, fwT);
    k_conv2<<<6272, 256, 0, stream>>>(Amat, hl, fwT, fb, out);
}

// Round 13
// 387.560 us; speedup vs baseline: 1.0090x; 1.0090x over previous
//
#include <hip/hip_runtime.h>
#include <hip/hip_bf16.h>
#include <cstdint>

#define AS1 __attribute__((address_space(1)))
#define AS3 __attribute__((address_space(3)))

typedef __bf16 bf16x8 __attribute__((ext_vector_type(8)));
typedef float  f32x16 __attribute__((ext_vector_type(16)));

__device__ __forceinline__ void gld_lds16(const void* g, void* l) {
    __builtin_amdgcn_global_load_lds((const AS1 void*)g, (AS3 void*)l, 16, 0, 0);
}

// ---------------- Kernel 1: conv1 + relu -> channel-last padded bf16 h ----------------
// Side jobs: blocks <1152 build GEMM A; blocks 1152..2327 build fwT[point][12]
// (transposed+padded fc_w: fwT[(a*784+rr)*12 + c] = fw[c*25088 + a*784 + rr], c<10).
// hl layout: [b][yy 0..29][xx 0..29][c 0..127], borders = 0.
__global__ __launch_bounds__(256) void k_conv1(const float* __restrict__ x,
                                               const float* __restrict__ base,
                                               const float* __restrict__ w2,
                                               const float* __restrict__ fw,
                                               __hip_bfloat16* __restrict__ hl,
                                               __hip_bfloat16* __restrict__ A,
                                               float* __restrict__ fwT) {
    int tid = threadIdx.x;

    if (blockIdx.x < 1152) {
        int i = blockIdx.x * 256 + tid;
        int r = i / 1152, k = i - r * 1152;
        int g = r >> 5, o2 = r & 31;
        int kk = k >> 7, cch = k & 127;
        int ky = kk / 3, kx = kk - ky * 3;
        int c2 = cch >> 3, hh = cch & 7;
        int gi = (g - hh) & 7;
        A[i] = __float2bfloat16(w2[((o2 * 16 + c2) * 8 + gi) * 9 + ky * 3 + kx]);
    } else if (blockIdx.x < 2328) {
        int i = (blockIdx.x - 1152) * 256 + tid;      // < 301056 = 25088*12 exact
        int point = i / 12, c = i - point * 12;
        fwT[i] = (c < 10) ? fw[c * 25088 + point] : 0.0f;
    }

    __shared__ float w1s[1152];
    if (tid < 128) {
        int g = tid >> 4, o = tid & 15;
        float th = 6.28318530717958647692f * (float)g / 8.0f;
        float c = cosf(th), s = sinf(th);
        for (int i = 0; i < 3; ++i) {
            float ys = (2.0f * i + 1.0f) / 3.0f - 1.0f;
            for (int j = 0; j < 3; ++j) {
                float xs = (2.0f * j + 1.0f) / 3.0f - 1.0f;
                float gx = c * xs - s * ys;
                float gy = s * xs + c * ys;
                float px = ((gx + 1.0f) * 3.0f - 1.0f) * 0.5f;
                float py = ((gy + 1.0f) * 3.0f - 1.0f) * 0.5f;
                float x0 = floorf(px), y0 = floorf(py);
                float wx = px - x0, wy = py - y0;
                int x0i = (int)x0, y0i = (int)y0;
                auto gat = [&](int yi, int xi) -> float {
                    bool v = (yi >= 0) && (yi < 3) && (xi >= 0) && (xi < 3);
                    int yc = min(max(yi, 0), 2), xc = min(max(xi, 0), 2);
                    return v ? base[o * 9 + yc * 3 + xc] : 0.0f;
                };
                w1s[tid * 9 + i * 3 + j] =
                      gat(y0i, x0i)         * (1.0f - wx) * (1.0f - wy)
                    + gat(y0i, x0i + 1)     * wx          * (1.0f - wy)
                    + gat(y0i + 1, x0i)     * (1.0f - wx) * wy
                    + gat(y0i + 1, x0i + 1) * wx          * wy;
            }
        }
    }
    __syncthreads();

    const int c0 = (tid & 15) * 8;
    float wreg[8][9];
#pragma unroll
    for (int cc = 0; cc < 8; ++cc)
#pragma unroll
        for (int k = 0; k < 9; ++k) wreg[cc][k] = w1s[(c0 + cc) * 9 + k];

    const int slot = tid >> 4;                    // 0..15
    const int band = blockIdx.x % 15;
    const int b    = blockIdx.x / 15;
    const int yy   = band * 2 + (slot >> 3);      // padded row 0..29
    const int xx0  = (slot & 7) * 4;              // 0,4,...,28

    const float* xb = x + b * 784;
    float xv[3][6];
#pragma unroll
    for (int t = 0; t < 3; ++t) {
        int sy = yy - 2 + t;
        bool syok = (sy >= 0) && (sy < 28);
#pragma unroll
        for (int u = 0; u < 6; ++u) {
            int sx = xx0 - 2 + u;
            bool ok = syok && (sx >= 0) && (sx < 28);
            xv[t][u] = ok ? xb[sy * 28 + sx] : 0.0f;
        }
    }

    float acc[4][8];
#pragma unroll
    for (int j = 0; j < 4; ++j)
#pragma unroll
        for (int cc = 0; cc < 8; ++cc) acc[j][cc] = 0.0f;

#pragma unroll
    for (int t = 0; t < 3; ++t)
#pragma unroll
        for (int u = 0; u < 3; ++u) {
#pragma unroll
            for (int j = 0; j < 4; ++j) {
                float xvv = xv[t][j + u];
#pragma unroll
                for (int cc = 0; cc < 8; ++cc)
                    acc[j][cc] += xvv * wreg[cc][t * 3 + u];
            }
        }

#pragma unroll
    for (int j = 0; j < 4; ++j) {
        int xx = xx0 + j;
        if (xx < 30) {
            bool interior = (yy >= 1) && (yy <= 28) && (xx >= 1) && (xx <= 28);
            union { __hip_bfloat16 h[8]; float4 f4; } u;
#pragma unroll
            for (int cc = 0; cc < 8; ++cc)
                u.h[cc] = __float2bfloat16(interior ? fmaxf(acc[j][cc], 0.0f) : 0.0f);
            int pi = b * 900 + yy * 30 + xx;
            *(float4*)(hl + (size_t)pi * 128 + c0) = u.f4;
        }
    }
}

// ---------------- Kernel 2: conv2 implicit GEMM (32x32x16) + relu + pool + FUSED FC ----
// R11 proven core: M=128 x N=128, BK=64, 18 stages, XCD-paired mt halves, conflict-free
// swizzle. Fused FC v4: coalesced fwT loads + LDS transpose reduction (no shfl trees).
__global__ __launch_bounds__(256) void k_conv2(const __hip_bfloat16* __restrict__ A,
                                               const __hip_bfloat16* __restrict__ hl,
                                               const float* __restrict__ fwT,
                                               const float* __restrict__ fb,
                                               float* __restrict__ out) {
    __shared__ __align__(16) char smem[32768];   // staging; reused as red[20][264] floats

    const int tid  = threadIdx.x;
    const int lane = tid & 63;
    const int w    = tid >> 6;
    const int wr   = w >> 1, wc = w & 1;
    const int hi   = lane >> 5;           // K-half selector

    const int bid  = blockIdx.x;          // grid 6272 = 8 * 784
    const int xcd  = bid & 7;
    const int slot = bid >> 3;
    const int nt   = xcd + 8 * (slot >> 1);   // < 3136
    const int mt   = slot & 1;
    const int n0 = nt << 7;
    const int r0 = mt << 7;

    uint32_t aG[4], bG[4], ldsOff[4];
#pragma unroll
    for (int q = 0; q < 4; ++q) {
        int ch = w * 4 + q;
        int rl = ch * 8 + (lane >> 3);
        int ca = (lane & 7) ^ (rl & 7) ^ (ch & 3);
        aG[q] = (uint32_t)((r0 + rl) * 2304 + ca * 16);
        int n  = n0 + rl;
        int b  = n / 784; int rr = n - b * 784;
        int y  = rr / 28; int xx = rr - y * 28;
        bG[q]  = (uint32_t)(((b * 30 + y) * 30 + xx) * 256 + ca * 16);
        ldsOff[q] = (uint32_t)(ch * 1024);
    }

    uint32_t aro[2], bro[2]; int asw[2], bsw[2];
#pragma unroll
    for (int t = 0; t < 2; ++t) {
        int rl = 64 * wr + 32 * t + (lane & 31);
        aro[t] = (uint32_t)(rl * 128); asw[t] = (rl & 7) ^ ((rl >> 3) & 3);
        int nl = 64 * wc + 32 * t + (lane & 31);
        bro[t] = (uint32_t)(16384 + nl * 128); bsw[t] = (nl & 7) ^ ((nl >> 3) & 3);
    }

    f32x16 acc[2][2];
#pragma unroll
    for (int i = 0; i < 2; ++i)
#pragma unroll
        for (int j = 0; j < 2; ++j) acc[i][j] = (f32x16)(0.0f);

    const char* Ab = (const char*)A;
    const char* Hb = (const char*)hl;

    for (int s = 0; s < 18; ++s) {
        int kk = s >> 1, half = s & 1;
        int ky = kk / 3, kx = kk - ky * 3;
        int aoff = kk * 256 + half * 128;
        int boff = (ky * 30 + kx) * 256 + half * 128;

        __syncthreads();
#pragma unroll
        for (int q = 0; q < 4; ++q) {
            gld_lds16(Ab + aG[q] + aoff, smem + ldsOff[q]);
            gld_lds16(Hb + bG[q] + boff, smem + 16384 + ldsOff[q]);
        }
        __syncthreads();

#pragma unroll
        for (int kstep = 0; kstep < 4; ++kstep) {
            int cb = kstep * 2 + hi;
            bf16x8 af[2], bf[2];
#pragma unroll
            for (int t = 0; t < 2; ++t) {
                af[t] = *(const bf16x8*)(smem + aro[t] + ((cb ^ asw[t]) * 16));
                bf[t] = *(const bf16x8*)(smem + bro[t] + ((cb ^ bsw[t]) * 16));
            }
#pragma unroll
            for (int i = 0; i < 2; ++i)
#pragma unroll
                for (int j = 0; j < 2; ++j)
                    acc[i][j] = __builtin_amdgcn_mfma_f32_32x32x16_bf16(af[i], bf[j], acc[i][j], 0, 0, 0);
        }
    }

    // ---------- epilogue: relu + 8-row mean -> fused FC (coalesced fwT) ----------
    float accfc[2][10];
    int bb_[2], rr_[2];
#pragma unroll
    for (int tj = 0; tj < 2; ++tj) {
#pragma unroll
        for (int c = 0; c < 10; ++c) accfc[tj][c] = 0.0f;
        int n = n0 + 64 * wc + 32 * tj + (lane & 31);
        int b = n / 784;
        bb_[tj] = b; rr_[tj] = n - b * 784;
    }
    const int qlo = hi * 2;   // hi==0 handles q 0,1; hi==1 handles q 2,3
#pragma unroll
    for (int ti = 0; ti < 2; ++ti) {
        int gbase = (r0 + 64 * wr + 32 * ti) >> 3;
#pragma unroll
        for (int tj = 0; tj < 2; ++tj) {
            f32x16 v = acc[ti][tj];
#pragma unroll
            for (int q = 0; q < 4; ++q) {
                float s = fmaxf(v[4*q], 0.0f) + fmaxf(v[4*q+1], 0.0f)
                        + fmaxf(v[4*q+2], 0.0f) + fmaxf(v[4*q+3], 0.0f);
                s += __shfl_xor(s, 32, 64);      // both halves hold pooled sum
                if (q >= qlo && q < qlo + 2) {
                    float sp = s * 0.125f;
                    int a = gbase + q;
                    const float4* fwp = (const float4*)(fwT + (size_t)(a * 784 + rr_[tj]) * 12);
                    float4 u0 = fwp[0], u1 = fwp[1], u2 = fwp[2];
                    accfc[tj][0] += sp * u0.x; accfc[tj][1] += sp * u0.y;
                    accfc[tj][2] += sp * u0.z; accfc[tj][3] += sp * u0.w;
                    accfc[tj][4] += sp * u1.x; accfc[tj][5] += sp * u1.y;
                    accfc[tj][6] += sp * u1.z; accfc[tj][7] += sp * u1.w;
                    accfc[tj][8] += sp * u2.x; accfc[tj][9] += sp * u2.y;
                }
            }
        }
    }

    // bucket by batch (tile spans <= 2 batches), constant-indexed
    const int b0 = n0 / 784;
    const bool sec0 = (bb_[0] != b0);
    const bool sec1 = (bb_[1] != b0);
    float val[20];
#pragma unroll
    for (int c = 0; c < 10; ++c) {
        float a0 = accfc[0][c], a1 = accfc[1][c];
        val[c]      = (sec0 ? 0.0f : a0) + (sec1 ? 0.0f : a1);
        val[10 + c] = (sec0 ? a0 : 0.0f) + (sec1 ? a1 : 0.0f);
    }

    // LDS transpose reduction: red[row][tid] stride 264; strided reads are 2-way max.
    float* red = (float*)smem;
    __syncthreads();                       // all waves done with smem frag reads
#pragma unroll
    for (int c = 0; c < 20; ++c) red[c * 264 + tid] = val[c];
    __syncthreads();
    if (tid < 160) {
        int row = tid >> 3, k = tid & 7;
        const float* rp = red + row * 264 + k;
        float s = 0.0f;
#pragma unroll
        for (int i = 0; i < 32; ++i) s += rp[8 * i];
        s += __shfl_down(s, 4, 8);
        s += __shfl_down(s, 2, 8);
        s += __shfl_down(s, 1, 8);
        if (k == 0) {
            int idx = row / 10, c = row - idx * 10;
            int b = b0 + idx;
            if (b < 512) {
                // bias added exactly once: by the mt==0 block containing batch b's pixel 0
                if (mt == 0 && b * 784 >= n0 && b * 784 < n0 + 128) s += fb[c];
                atomicAdd(&out[b * 10 + c], s);
            }
        }
    }
}

// ---------------- launch ----------------
extern "C" void kernel_launch(void* const* d_in, const int* in_sizes, int n_in,
                              void* d_out, int out_size, void* d_ws, size_t ws_size,
                              hipStream_t stream) {
    const float* x  = (const float*)d_in[0];
    const float* bw = (const float*)d_in[1];
    const float* w2 = (const float*)d_in[2];
    const float* fw = (const float*)d_in[3];
    const float* fb = (const float*)d_in[4];
    float* out = (float*)d_out;
    char* ws = (char*)d_ws;

    __hip_bfloat16* Amat = (__hip_bfloat16*)(ws + 4608);
    __hip_bfloat16* hl   = (__hip_bfloat16*)(ws + 594432);
    float*          fwT  = (float*)(ws + 118563328);

    hipMemsetAsync(d_out, 0, (size_t)out_size * sizeof(float), stream);
    k_conv1<<<7680, 256, 0, stream>>>(x, bw, w2, fw, hl, Amat, fwT);
    k_conv2<<<6272, 256, 0, stream>>>(Amat, hl, fwT, fb, out);
}

// Round 14
// 367.311 us; speedup vs baseline: 1.0646x; 1.0551x over previous
//
#include <hip/hip_runtime.h>
#include <hip/hip_bf16.h>
#include <cstdint>

#define AS1 __attribute__((address_space(1)))
#define AS3 __attribute__((address_space(3)))

typedef __bf16 bf16x8 __attribute__((ext_vector_type(8)));
typedef float  f32x16 __attribute__((ext_vector_type(16)));

__device__ __forceinline__ void gld_lds16(const void* g, void* l) {
    __builtin_amdgcn_global_load_lds((const AS1 void*)g, (AS3 void*)l, 16, 0, 0);
}

// ---------------- Kernel 0: rotated 3x3 kernels (exact fp32 replica), ONCE ----------------
__global__ void k_rot(const float* __restrict__ base, float* __restrict__ w1) {
    int m = threadIdx.x;            // 0..127 = g*16+o
    int g = m >> 4, o = m & 15;
    float th = 6.28318530717958647692f * (float)g / 8.0f;
    float c = cosf(th), s = sinf(th);
    for (int i = 0; i < 3; ++i) {
        float ys = (2.0f * i + 1.0f) / 3.0f - 1.0f;
        for (int j = 0; j < 3; ++j) {
            float xs = (2.0f * j + 1.0f) / 3.0f - 1.0f;
            float gx = c * xs - s * ys;
            float gy = s * xs + c * ys;
            float px = ((gx + 1.0f) * 3.0f - 1.0f) * 0.5f;
            float py = ((gy + 1.0f) * 3.0f - 1.0f) * 0.5f;
            float x0 = floorf(px), y0 = floorf(py);
            float wx = px - x0, wy = py - y0;
            int x0i = (int)x0, y0i = (int)y0;
            auto gat = [&](int yi, int xi) -> float {
                bool v = (yi >= 0) && (yi < 3) && (xi >= 0) && (xi < 3);
                int yc = min(max(yi, 0), 2), xc = min(max(xi, 0), 2);
                return v ? base[o * 9 + yc * 3 + xc] : 0.0f;
            };
            w1[m * 9 + i * 3 + j] =
                  gat(y0i, x0i)         * (1.0f - wx) * (1.0f - wy)
                + gat(y0i, x0i + 1)     * wx          * (1.0f - wy)
                + gat(y0i + 1, x0i)     * (1.0f - wx) * wy
                + gat(y0i + 1, x0i + 1) * wx          * wy;
        }
    }
}

// ---------------- Kernel 1: conv1 + relu -> channel-last padded bf16 h ----------------
// Loads precomputed w1 (no per-block rotation recompute — that cost ~35 us chip-wide).
// Blocks <1152 also build the bf16 GEMM A matrix.
// hl layout: [b][yy 0..29][xx 0..29][c 0..127], borders = 0.
__global__ __launch_bounds__(256) void k_conv1(const float* __restrict__ x,
                                               const float* __restrict__ w1g,
                                               const float* __restrict__ w2,
                                               __hip_bfloat16* __restrict__ hl,
                                               __hip_bfloat16* __restrict__ A) {
    int tid = threadIdx.x;

    if (blockIdx.x < 1152) {
        int i = blockIdx.x * 256 + tid;
        int r = i / 1152, k = i - r * 1152;
        int g = r >> 5, o2 = r & 31;
        int kk = k >> 7, cch = k & 127;
        int ky = kk / 3, kx = kk - ky * 3;
        int c2 = cch >> 3, hh = cch & 7;
        int gi = (g - hh) & 7;
        A[i] = __float2bfloat16(w2[((o2 * 16 + c2) * 8 + gi) * 9 + ky * 3 + kx]);
    }

    __shared__ float w1s[1152];
    for (int i = tid; i < 1152; i += 256) w1s[i] = w1g[i];
    __syncthreads();

    const int c0 = (tid & 15) * 8;
    float wreg[8][9];
#pragma unroll
    for (int cc = 0; cc < 8; ++cc)
#pragma unroll
        for (int k = 0; k < 9; ++k) wreg[cc][k] = w1s[(c0 + cc) * 9 + k];

    const int slot = tid >> 4;                    // 0..15
    const int band = blockIdx.x % 15;
    const int b    = blockIdx.x / 15;
    const int yy   = band * 2 + (slot >> 3);      // padded row 0..29
    const int xx0  = (slot & 7) * 4;              // 0,4,...,28

    const float* xb = x + b * 784;
    float xv[3][6];
#pragma unroll
    for (int t = 0; t < 3; ++t) {
        int sy = yy - 2 + t;
        bool syok = (sy >= 0) && (sy < 28);
#pragma unroll
        for (int u = 0; u < 6; ++u) {
            int sx = xx0 - 2 + u;
            bool ok = syok && (sx >= 0) && (sx < 28);
            xv[t][u] = ok ? xb[sy * 28 + sx] : 0.0f;
        }
    }

    float acc[4][8];
#pragma unroll
    for (int j = 0; j < 4; ++j)
#pragma unroll
        for (int cc = 0; cc < 8; ++cc) acc[j][cc] = 0.0f;

#pragma unroll
    for (int t = 0; t < 3; ++t)
#pragma unroll
        for (int u = 0; u < 3; ++u) {
#pragma unroll
            for (int j = 0; j < 4; ++j) {
                float xvv = xv[t][j + u];
#pragma unroll
                for (int cc = 0; cc < 8; ++cc)
                    acc[j][cc] += xvv * wreg[cc][t * 3 + u];
            }
        }

#pragma unroll
    for (int j = 0; j < 4; ++j) {
        int xx = xx0 + j;
        if (xx < 30) {
            bool interior = (yy >= 1) && (yy <= 28) && (xx >= 1) && (xx <= 28);
            union { __hip_bfloat16 h[8]; float4 f4; } u;
#pragma unroll
            for (int cc = 0; cc < 8; ++cc)
                u.h[cc] = __float2bfloat16(interior ? fmaxf(acc[j][cc], 0.0f) : 0.0f);
            int pi = b * 900 + yy * 30 + xx;
            *(float4*)(hl + (size_t)pi * 128 + c0) = u.f4;
        }
    }
}

// ---------------- Kernel 2: conv2 implicit GEMM (32x32x16) + relu + pool -> p(bf16) ----
// R11 proven core: M=128 x N=128, BK=64, 18 stages, XCD-paired mt halves,
// conflict-free swizzle (r&7)^((r>>3)&3). Dense-N: n = b*784 + y*28 + x.
__global__ __launch_bounds__(256) void k_conv2(const __hip_bfloat16* __restrict__ A,
                                               const __hip_bfloat16* __restrict__ hl,
                                               __hip_bfloat16* __restrict__ p) {
    __shared__ __align__(16) char smem[32768];   // As [128][64] bf16 | Bs [128][64] bf16

    const int tid  = threadIdx.x;
    const int lane = tid & 63;
    const int w    = tid >> 6;
    const int wr   = w >> 1, wc = w & 1;
    const int hi   = lane >> 5;           // K-half selector

    const int bid  = blockIdx.x;          // grid 6272 = 8 * 784
    const int xcd  = bid & 7;
    const int slot = bid >> 3;
    const int nt   = xcd + 8 * (slot >> 1);   // < 3136
    const int mt   = slot & 1;
    const int n0 = nt << 7;
    const int r0 = mt << 7;

    uint32_t aG[4], bG[4], ldsOff[4];
#pragma unroll
    for (int q = 0; q < 4; ++q) {
        int ch = w * 4 + q;
        int rl = ch * 8 + (lane >> 3);
        int ca = (lane & 7) ^ (rl & 7) ^ (ch & 3);
        aG[q] = (uint32_t)((r0 + rl) * 2304 + ca * 16);
        int n  = n0 + rl;
        int b  = n / 784; int rr = n - b * 784;
        int y  = rr / 28; int xx = rr - y * 28;
        bG[q]  = (uint32_t)(((b * 30 + y) * 30 + xx) * 256 + ca * 16);
        ldsOff[q] = (uint32_t)(ch * 1024);
    }

    uint32_t aro[2], bro[2]; int asw[2], bsw[2];
#pragma unroll
    for (int t = 0; t < 2; ++t) {
        int rl = 64 * wr + 32 * t + (lane & 31);
        aro[t] = (uint32_t)(rl * 128); asw[t] = (rl & 7) ^ ((rl >> 3) & 3);
        int nl = 64 * wc + 32 * t + (lane & 31);
        bro[t] = (uint32_t)(16384 + nl * 128); bsw[t] = (nl & 7) ^ ((nl >> 3) & 3);
    }

    f32x16 acc[2][2];
#pragma unroll
    for (int i = 0; i < 2; ++i)
#pragma unroll
        for (int j = 0; j < 2; ++j) acc[i][j] = (f32x16)(0.0f);

    const char* Ab = (const char*)A;
    const char* Hb = (const char*)hl;

    for (int s = 0; s < 18; ++s) {
        int kk = s >> 1, half = s & 1;
        int ky = kk / 3, kx = kk - ky * 3;
        int aoff = kk * 256 + half * 128;
        int boff = (ky * 30 + kx) * 256 + half * 128;

        __syncthreads();
#pragma unroll
        for (int q = 0; q < 4; ++q) {
            gld_lds16(Ab + aG[q] + aoff, smem + ldsOff[q]);
            gld_lds16(Hb + bG[q] + boff, smem + 16384 + ldsOff[q]);
        }
        __syncthreads();

#pragma unroll
        for (int kstep = 0; kstep < 4; ++kstep) {
            int cb = kstep * 2 + hi;
            bf16x8 af[2], bf[2];
#pragma unroll
            for (int t = 0; t < 2; ++t) {
                af[t] = *(const bf16x8*)(smem + aro[t] + ((cb ^ asw[t]) * 16));
                bf[t] = *(const bf16x8*)(smem + bro[t] + ((cb ^ bsw[t]) * 16));
            }
#pragma unroll
            for (int i = 0; i < 2; ++i)
#pragma unroll
                for (int j = 0; j < 2; ++j)
                    acc[i][j] = __builtin_amdgcn_mfma_f32_32x32x16_bf16(af[i], bf[j], acc[i][j], 0, 0, 0);
        }
    }

    // epilogue: relu + mean over 8 consecutive M-rows; bf16 store.
#pragma unroll
    for (int ti = 0; ti < 2; ++ti) {
        int gbase = (r0 + 64 * wr + 32 * ti) >> 3;
#pragma unroll
        for (int tj = 0; tj < 2; ++tj) {
            f32x16 v = acc[ti][tj];
#pragma unroll
            for (int q = 0; q < 4; ++q) {
                float s = fmaxf(v[4*q], 0.0f) + fmaxf(v[4*q+1], 0.0f)
                        + fmaxf(v[4*q+2], 0.0f) + fmaxf(v[4*q+3], 0.0f);
                s += __shfl_xor(s, 32, 64);
                if (hi == 0) {
                    int a = gbase + q;
                    int n = n0 + 64 * wc + 32 * tj + (lane & 31);
                    int b = n / 784; int rr = n - b * 784;
                    p[(b * 32 + a) * 784 + rr] = __float2bfloat16(s * 0.125f);
                }
            }
        }
    }
}

// ---------------- Kernel 3: FC — 4-way k-split, bf16 p reads (R11 proven) ----------------
__global__ __launch_bounds__(256) void k_fc(const __hip_bfloat16* __restrict__ p,
                                            const float* __restrict__ fw,
                                            const float* __restrict__ fb,
                                            float* __restrict__ out) {
    int b = blockIdx.x >> 2, ks = blockIdx.x & 3;
    int tid = threadIdx.x;
    const bf16x8* pb = (const bf16x8*)(p + (size_t)b * 25088);
    const float4* w4 = (const float4*)fw;
    float acc[10] = {};
    for (int t = ks * 784 + tid; t < (ks + 1) * 784; t += 256) {
        union { bf16x8 v; __hip_bfloat16 h[8]; } u;
        u.v = pb[t];
        float vf[8];
#pragma unroll
        for (int e = 0; e < 8; ++e) vf[e] = __bfloat162float(u.h[e]);
#pragma unroll
        for (int c = 0; c < 10; ++c) {
            float4 u0 = w4[c * 6272 + 2 * t];
            float4 u1 = w4[c * 6272 + 2 * t + 1];
            acc[c] += vf[0] * u0.x + vf[1] * u0.y + vf[2] * u0.z + vf[3] * u0.w
                    + vf[4] * u1.x + vf[5] * u1.y + vf[6] * u1.z + vf[7] * u1.w;
        }
    }
    __shared__ float red[10][4];
    int lane = tid & 63, wv = tid >> 6;
#pragma unroll
    for (int c = 0; c < 10; ++c) {
        float s = acc[c];
#pragma unroll
        for (int o = 32; o > 0; o >>= 1) s += __shfl_down(s, o, 64);
        if (lane == 0) red[c][wv] = s;
    }
    __syncthreads();
    if (tid < 10) {
        float s = red[tid][0] + red[tid][1] + red[tid][2] + red[tid][3];
        if (ks == 0) s += fb[tid];
        atomicAdd(&out[b * 10 + tid], s);
    }
}

// ---------------- launch ----------------
extern "C" void kernel_launch(void* const* d_in, const int* in_sizes, int n_in,
                              void* d_out, int out_size, void* d_ws, size_t ws_size,
                              hipStream_t stream) {
    const float* x  = (const float*)d_in[0];
    const float* bw = (const float*)d_in[1];
    const float* w2 = (const float*)d_in[2];
    const float* fw = (const float*)d_in[3];
    const float* fb = (const float*)d_in[4];
    float* out = (float*)d_out;
    char* ws = (char*)d_ws;

    float*          w1   = (float*)(ws);
    __hip_bfloat16* Amat = (__hip_bfloat16*)(ws + 4608);
    __hip_bfloat16* hl   = (__hip_bfloat16*)(ws + 594432);
    __hip_bfloat16* p    = (__hip_bfloat16*)(ws + 118563328);

    hipMemsetAsync(d_out, 0, (size_t)out_size * sizeof(float), stream);
    k_rot  <<<1,    128, 0, stream>>>(bw, w1);
    k_conv1<<<7680, 256, 0, stream>>>(x, w1, w2, hl, Amat);
    k_conv2<<<6272, 256, 0, stream>>>(Amat, hl, p);
    k_fc   <<<2048, 256, 0, stream>>>(p, fw, fb, out);
}

// Round 15
// 366.238 us; speedup vs baseline: 1.0678x; 1.0029x over previous
//
#include <hip/hip_runtime.h>
#include <hip/hip_bf16.h>
#include <cstdint>

#define AS1 __attribute__((address_space(1)))
#define AS3 __attribute__((address_space(3)))

typedef __bf16 bf16x8 __attribute__((ext_vector_type(8)));
typedef float  f32x16 __attribute__((ext_vector_type(16)));

__device__ __forceinline__ void gld_lds16(const void* g, void* l) {
    __builtin_amdgcn_global_load_lds((const AS1 void*)g, (AS3 void*)l, 16, 0, 0);
}

// ---------------- Kernel 0: rotated 3x3 kernels (exact fp32 replica), ONCE ----------------
__global__ void k_rot(const float* __restrict__ base, float* __restrict__ w1) {
    int m = threadIdx.x;            // 0..127 = g*16+o
    int g = m >> 4, o = m & 15;
    float th = 6.28318530717958647692f * (float)g / 8.0f;
    float c = cosf(th), s = sinf(th);
    for (int i = 0; i < 3; ++i) {
        float ys = (2.0f * i + 1.0f) / 3.0f - 1.0f;
        for (int j = 0; j < 3; ++j) {
            float xs = (2.0f * j + 1.0f) / 3.0f - 1.0f;
            float gx = c * xs - s * ys;
            float gy = s * xs + c * ys;
            float px = ((gx + 1.0f) * 3.0f - 1.0f) * 0.5f;
            float py = ((gy + 1.0f) * 3.0f - 1.0f) * 0.5f;
            float x0 = floorf(px), y0 = floorf(py);
            float wx = px - x0, wy = py - y0;
            int x0i = (int)x0, y0i = (int)y0;
            auto gat = [&](int yi, int xi) -> float {
                bool v = (yi >= 0) && (yi < 3) && (xi >= 0) && (xi < 3);
                int yc = min(max(yi, 0), 2), xc = min(max(xi, 0), 2);
                return v ? base[o * 9 + yc * 3 + xc] : 0.0f;
            };
            w1[m * 9 + i * 3 + j] =
                  gat(y0i, x0i)         * (1.0f - wx) * (1.0f - wy)
                + gat(y0i, x0i + 1)     * wx          * (1.0f - wy)
                + gat(y0i + 1, x0i)     * (1.0f - wx) * wy
                + gat(y0i + 1, x0i + 1) * wx          * wy;
        }
    }
}

// ---------------- Kernel 1: conv1 + relu -> channel-last padded bf16 h ----------------
// Loads precomputed w1. Blocks <1152 also build the bf16 GEMM A matrix.
// hl layout: [b][yy 0..29][xx 0..29][c 0..127], borders = 0.
__global__ __launch_bounds__(256) void k_conv1(const float* __restrict__ x,
                                               const float* __restrict__ w1g,
                                               const float* __restrict__ w2,
                                               __hip_bfloat16* __restrict__ hl,
                                               __hip_bfloat16* __restrict__ A) {
    int tid = threadIdx.x;

    if (blockIdx.x < 1152) {
        int i = blockIdx.x * 256 + tid;
        int r = i / 1152, k = i - r * 1152;
        int g = r >> 5, o2 = r & 31;
        int kk = k >> 7, cch = k & 127;
        int ky = kk / 3, kx = kk - ky * 3;
        int c2 = cch >> 3, hh = cch & 7;
        int gi = (g - hh) & 7;
        A[i] = __float2bfloat16(w2[((o2 * 16 + c2) * 8 + gi) * 9 + ky * 3 + kx]);
    }

    __shared__ float w1s[1152];
    for (int i = tid; i < 1152; i += 256) w1s[i] = w1g[i];
    __syncthreads();

    const int c0 = (tid & 15) * 8;
    float wreg[8][9];
#pragma unroll
    for (int cc = 0; cc < 8; ++cc)
#pragma unroll
        for (int k = 0; k < 9; ++k) wreg[cc][k] = w1s[(c0 + cc) * 9 + k];

    const int slot = tid >> 4;                    // 0..15
    const int band = blockIdx.x % 15;
    const int b    = blockIdx.x / 15;
    const int yy   = band * 2 + (slot >> 3);      // padded row 0..29
    const int xx0  = (slot & 7) * 4;              // 0,4,...,28

    const float* xb = x + b * 784;
    float xv[3][6];
#pragma unroll
    for (int t = 0; t < 3; ++t) {
        int sy = yy - 2 + t;
        bool syok = (sy >= 0) && (sy < 28);
#pragma unroll
        for (int u = 0; u < 6; ++u) {
            int sx = xx0 - 2 + u;
            bool ok = syok && (sx >= 0) && (sx < 28);
            xv[t][u] = ok ? xb[sy * 28 + sx] : 0.0f;
        }
    }

    float acc[4][8];
#pragma unroll
    for (int j = 0; j < 4; ++j)
#pragma unroll
        for (int cc = 0; cc < 8; ++cc) acc[j][cc] = 0.0f;

#pragma unroll
    for (int t = 0; t < 3; ++t)
#pragma unroll
        for (int u = 0; u < 3; ++u) {
#pragma unroll
            for (int j = 0; j < 4; ++j) {
                float xvv = xv[t][j + u];
#pragma unroll
                for (int cc = 0; cc < 8; ++cc)
                    acc[j][cc] += xvv * wreg[cc][t * 3 + u];
            }
        }

#pragma unroll
    for (int j = 0; j < 4; ++j) {
        int xx = xx0 + j;
        if (xx < 30) {
            bool interior = (yy >= 1) && (yy <= 28) && (xx >= 1) && (xx <= 28);
            union { __hip_bfloat16 h[8]; float4 f4; } u;
#pragma unroll
            for (int cc = 0; cc < 8; ++cc)
                u.h[cc] = __float2bfloat16(interior ? fmaxf(acc[j][cc], 0.0f) : 0.0f);
            int pi = b * 900 + yy * 30 + xx;
            *(float4*)(hl + (size_t)pi * 128 + c0) = u.f4;
        }
    }
}

// ---------------- Kernel 2: conv2 implicit GEMM (32x32x16) + relu + pool -> p(bf16) ----
// R14 core + __launch_bounds__(256,4): force <=128 regs/thread (64 VGPR + 64 acc)
// for 4 blocks/CU — more co-resident blocks to overlap the barrier drain.
__global__ __launch_bounds__(256, 4) void k_conv2(const __hip_bfloat16* __restrict__ A,
                                                  const __hip_bfloat16* __restrict__ hl,
                                                  __hip_bfloat16* __restrict__ p) {
    __shared__ __align__(16) char smem[32768];   // As [128][64] bf16 | Bs [128][64] bf16

    const int tid  = threadIdx.x;
    const int lane = tid & 63;
    const int w    = tid >> 6;
    const int wr   = w >> 1, wc = w & 1;
    const int hi   = lane >> 5;           // K-half selector

    const int bid  = blockIdx.x;          // grid 6272 = 8 * 784
    const int xcd  = bid & 7;
    const int slot = bid >> 3;
    const int nt   = xcd + 8 * (slot >> 1);   // < 3136
    const int mt   = slot & 1;
    const int n0 = nt << 7;
    const int r0 = mt << 7;

    uint32_t aG[4], bG[4], ldsOff[4];
#pragma unroll
    for (int q = 0; q < 4; ++q) {
        int ch = w * 4 + q;
        int rl = ch * 8 + (lane >> 3);
        int ca = (lane & 7) ^ (rl & 7) ^ (ch & 3);
        aG[q] = (uint32_t)((r0 + rl) * 2304 + ca * 16);
        int n  = n0 + rl;
        int b  = n / 784; int rr = n - b * 784;
        int y  = rr / 28; int xx = rr - y * 28;
        bG[q]  = (uint32_t)(((b * 30 + y) * 30 + xx) * 256 + ca * 16);
        ldsOff[q] = (uint32_t)(ch * 1024);
    }

    uint32_t aro[2], bro[2]; int asw[2], bsw[2];
#pragma unroll
    for (int t = 0; t < 2; ++t) {
        int rl = 64 * wr + 32 * t + (lane & 31);
        aro[t] = (uint32_t)(rl * 128); asw[t] = (rl & 7) ^ ((rl >> 3) & 3);
        int nl = 64 * wc + 32 * t + (lane & 31);
        bro[t] = (uint32_t)(16384 + nl * 128); bsw[t] = (nl & 7) ^ ((nl >> 3) & 3);
    }

    f32x16 acc[2][2];
#pragma unroll
    for (int i = 0; i < 2; ++i)
#pragma unroll
        for (int j = 0; j < 2; ++j) acc[i][j] = (f32x16)(0.0f);

    const char* Ab = (const char*)A;
    const char* Hb = (const char*)hl;

    for (int s = 0; s < 18; ++s) {
        int kk = s >> 1, half = s & 1;
        int ky = kk / 3, kx = kk - ky * 3;
        int aoff = kk * 256 + half * 128;
        int boff = (ky * 30 + kx) * 256 + half * 128;

        __syncthreads();
#pragma unroll
        for (int q = 0; q < 4; ++q) {
            gld_lds16(Ab + aG[q] + aoff, smem + ldsOff[q]);
            gld_lds16(Hb + bG[q] + boff, smem + 16384 + ldsOff[q]);
        }
        __syncthreads();

#pragma unroll
        for (int kstep = 0; kstep < 4; ++kstep) {
            int cb = kstep * 2 + hi;
            bf16x8 af[2], bf[2];
#pragma unroll
            for (int t = 0; t < 2; ++t) {
                af[t] = *(const bf16x8*)(smem + aro[t] + ((cb ^ asw[t]) * 16));
                bf[t] = *(const bf16x8*)(smem + bro[t] + ((cb ^ bsw[t]) * 16));
            }
#pragma unroll
            for (int i = 0; i < 2; ++i)
#pragma unroll
                for (int j = 0; j < 2; ++j)
                    acc[i][j] = __builtin_amdgcn_mfma_f32_32x32x16_bf16(af[i], bf[j], acc[i][j], 0, 0, 0);
        }
    }

    // epilogue: relu + mean over 8 consecutive M-rows; bf16 store.
#pragma unroll
    for (int ti = 0; ti < 2; ++ti) {
        int gbase = (r0 + 64 * wr + 32 * ti) >> 3;
#pragma unroll
        for (int tj = 0; tj < 2; ++tj) {
            f32x16 v = acc[ti][tj];
#pragma unroll
            for (int q = 0; q < 4; ++q) {
                float s = fmaxf(v[4*q], 0.0f) + fmaxf(v[4*q+1], 0.0f)
                        + fmaxf(v[4*q+2], 0.0f) + fmaxf(v[4*q+3], 0.0f);
                s += __shfl_xor(s, 32, 64);
                if (hi == 0) {
                    int a = gbase + q;
                    int n = n0 + 64 * wc + 32 * tj + (lane & 31);
                    int b = n / 784; int rr = n - b * 784;
                    p[(b * 32 + a) * 784 + rr] = __float2bfloat16(s * 0.125f);
                }
            }
        }
    }
}

// ---------------- Kernel 3: FC — 4-way k-split, bf16 p reads ----------------
__global__ __launch_bounds__(256) void k_fc(const __hip_bfloat16* __restrict__ p,
                                            const float* __restrict__ fw,
                                            const float* __restrict__ fb,
                                            float* __restrict__ out) {
    int b = blockIdx.x >> 2, ks = blockIdx.x & 3;
    int tid = threadIdx.x;
    const bf16x8* pb = (const bf16x8*)(p + (size_t)b * 25088);
    const float4* w4 = (const float4*)fw;
    float acc[10] = {};
    for (int t = ks * 784 + tid; t < (ks + 1) * 784; t += 256) {
        union { bf16x8 v; __hip_bfloat16 h[8]; } u;
        u.v = pb[t];
        float vf[8];
#pragma unroll
        for (int e = 0; e < 8; ++e) vf[e] = __bfloat162float(u.h[e]);
#pragma unroll
        for (int c = 0; c < 10; ++c) {
            float4 u0 = w4[c * 6272 + 2 * t];
            float4 u1 = w4[c * 6272 + 2 * t + 1];
            acc[c] += vf[0] * u0.x + vf[1] * u0.y + vf[2] * u0.z + vf[3] * u0.w
                    + vf[4] * u1.x + vf[5] * u1.y + vf[6] * u1.z + vf[7] * u1.w;
        }
    }
    __shared__ float red[10][4];
    int lane = tid & 63, wv = tid >> 6;
#pragma unroll
    for (int c = 0; c < 10; ++c) {
        float s = acc[c];
#pragma unroll
        for (int o = 32; o > 0; o >>= 1) s += __shfl_down(s, o, 64);
        if (lane == 0) red[c][wv] = s;
    }
    __syncthreads();
    if (tid < 10) {
        float s = red[tid][0] + red[tid][1] + red[tid][2] + red[tid][3];
        if (ks == 0) s += fb[tid];
        atomicAdd(&out[b * 10 + tid], s);
    }
}

// ---------------- launch ----------------
extern "C" void kernel_launch(void* const* d_in, const int* in_sizes, int n_in,
                              void* d_out, int out_size, void* d_ws, size_t ws_size,
                              hipStream_t stream) {
    const float* x  = (const float*)d_in[0];
    const float* bw = (const float*)d_in[1];
    const float* w2 = (const float*)d_in[2];
    const float* fw = (const float*)d_in[3];
    const float* fb = (const float*)d_in[4];
    float* out = (float*)d_out;
    char* ws = (char*)d_ws;

    float*          w1   = (float*)(ws);
    __hip_bfloat16* Amat = (__hip_bfloat16*)(ws + 4608);
    __hip_bfloat16* hl   = (__hip_bfloat16*)(ws + 594432);
    __hip_bfloat16* p    = (__hip_bfloat16*)(ws + 118563328);

    hipMemsetAsync(d_out, 0, (size_t)out_size * sizeof(float), stream);
    k_rot  <<<1,    128, 0, stream>>>(bw, w1);
    k_conv1<<<7680, 256, 0, stream>>>(x, w1, w2, hl, Amat);
    k_conv2<<<6272, 256, 0, stream>>>(Amat, hl, p);
    k_fc   <<<2048, 256, 0, stream>>>(p, fw, fb, out);
}